// Round 2
// baseline (480.359 us; speedup 1.0000x reference)
//
#include <hip/hip_runtime.h>
#include <math.h>

#define NROWS 32768
#define DCOLS 2048
#define EPS 1e-6f

typedef float vfloat4 __attribute__((ext_vector_type(4)));

// ---------------- Kernel 1: per-column sum of squares ----------------
// Block: 256 threads, each thread handles 4 consecutive columns (float4).
// Grid: (DCOLS/1024, NROWS/ROWS_PER_BLOCK). Atomic accumulate into u[DCOLS].
#define ROWS_PER_BLOCK 128

__global__ __launch_bounds__(256) void colsumsq_kernel(
    const float* __restrict__ x, float* __restrict__ u)
{
    const int c  = blockIdx.x * 1024 + threadIdx.x * 4;   // column base
    const int r0 = blockIdx.y * ROWS_PER_BLOCK;

    const vfloat4* p = (const vfloat4*)(x + (size_t)r0 * DCOLS + c);
    const size_t row_stride = DCOLS / 4;   // in float4 units

    float a0 = 0.f, a1 = 0.f, a2 = 0.f, a3 = 0.f;
    #pragma unroll 8
    for (int r = 0; r < ROWS_PER_BLOCK; ++r) {
        vfloat4 v = p[(size_t)r * row_stride];
        a0 += v.x * v.x;
        a1 += v.y * v.y;
        a2 += v.z * v.z;
        a3 += v.w * v.w;
    }
    atomicAdd(&u[c + 0], a0);
    atomicAdd(&u[c + 1], a1);
    atomicAdd(&u[c + 2], a2);
    atomicAdd(&u[c + 3], a3);
}

// ---------------- Kernel 2: scale columns by rsqrt(u + eps) ----------------
// One float4 per thread; u[] (8 KiB) lives in L1 after first touch.
// Non-temporal stores keep x resident in L3 (x is exactly L3-sized).
__global__ __launch_bounds__(256) void scale_kernel(
    const float* __restrict__ x, const float* __restrict__ u,
    float* __restrict__ out)
{
    const size_t i = ((size_t)blockIdx.x * 256 + threadIdx.x) * 4;
    const int c = (int)(i & (DCOLS - 1));   // column of element i (D divides 4-aligned)

    vfloat4 v = *(const vfloat4*)(x + i);
    vfloat4 s = *(const vfloat4*)(u + c);

    vfloat4 o;
    o.x = v.x * rsqrtf(s.x + EPS);
    o.y = v.y * rsqrtf(s.y + EPS);
    o.z = v.z * rsqrtf(s.z + EPS);
    o.w = v.w * rsqrtf(s.w + EPS);

    __builtin_nontemporal_store(o, (vfloat4*)(out + i));
}

extern "C" void kernel_launch(void* const* d_in, const int* in_sizes, int n_in,
                              void* d_out, int out_size, void* d_ws, size_t ws_size,
                              hipStream_t stream) {
    const float* x = (const float*)d_in[0];
    float* out = (float*)d_out;
    float* u = (float*)d_ws;   // DCOLS floats of scratch (8 KiB)

    // zero the accumulator (ws is re-poisoned to 0xAA before every launch)
    (void)hipMemsetAsync(u, 0, DCOLS * sizeof(float), stream);

    // pass 1: column sum of squares
    dim3 g1(DCOLS / 1024, NROWS / ROWS_PER_BLOCK);
    colsumsq_kernel<<<g1, 256, 0, stream>>>(x, u);

    // pass 2: scale
    const size_t total4 = (size_t)NROWS * DCOLS / 4;       // 16,777,216 float4s
    const int blocks2 = (int)(total4 / 256);               // 65,536 blocks
    scale_kernel<<<blocks2, 256, 0, stream>>>(x, u, out);
}